// Round 7
// baseline (138.645 us; speedup 1.0000x reference)
//
#include <hip/hip_runtime.h>

#define NN 2048     // nodes per graph
#define NG 64       // graphs
#define NE 16384    // edges per graph
#define BB 65536    // batch
#define META 64
#define TXD 8
#define NOISE 128

// ws layout: [0, 32KB) graph_out [64][128]

// ---------------------------------------------------------------------------
// Kernel A: per-graph GCN aggregation + fold, fused. One block per graph.
// deg: native int LDS atomics; agg: u64 fixed-point (x 2^40) ds_add_u64.
// emb stays in LDS; fold = emb @ emb_W[0:2048] done with broadcast-emb +
// coalesced float4 W loads, LDS-reduced, direct graph_out store.
// ---------------------------------------------------------------------------
__global__ __launch_bounds__(256) void agg_fold_kernel(
    const int* __restrict__ edges,     // [64,2,16384]
    const float* __restrict__ gcn_w,
    const float* __restrict__ gcn_b,
    const float* __restrict__ emb_W,   // [2089,128]
    float* __restrict__ graph_out)     // [64,128] (ws, direct store)
{
    __shared__ int                s_cnt[NN];     // 8 KB
    __shared__ float              s_emb[NN];     // 8 KB (dinv, then emb)
    __shared__ unsigned long long s_acc[NN];     // 16 KB
    __shared__ float              s_part[8][NOISE];  // 4 KB fold partials
    const int g = blockIdx.x, tid = threadIdx.x;
    const int4* __restrict__ e4 = (const int4*)(edges + (size_t)g * 2 * NE);

    int4 ds[16];
    #pragma unroll
    for (int k = 0; k < 16; ++k) ds[k] = e4[4096 + k * 256 + tid];

    for (int n = tid; n < NN; n += 256) { s_cnt[n] = 1; s_acc[n] = 0ull; }
    __syncthreads();

    #pragma unroll
    for (int k = 0; k < 16; ++k) {
        atomicAdd(&s_cnt[ds[k].x], 1);
        atomicAdd(&s_cnt[ds[k].y], 1);
        atomicAdd(&s_cnt[ds[k].z], 1);
        atomicAdd(&s_cnt[ds[k].w], 1);
    }
    __syncthreads();
    for (int n = tid; n < NN; n += 256) s_emb[n] = rsqrtf((float)s_cnt[n]);
    __syncthreads();

    const float SCALE = 1099511627776.0f;  // 2^40
    #pragma unroll
    for (int k = 0; k < 16; ++k) {
        int4 sr = e4[k * 256 + tid];
        float nx = s_emb[sr.x] * s_emb[ds[k].x];
        float ny = s_emb[sr.y] * s_emb[ds[k].y];
        float nz = s_emb[sr.z] * s_emb[ds[k].z];
        float nw = s_emb[sr.w] * s_emb[ds[k].w];
        atomicAdd(&s_acc[ds[k].x], (unsigned long long)(nx * SCALE));
        atomicAdd(&s_acc[ds[k].y], (unsigned long long)(ny * SCALE));
        atomicAdd(&s_acc[ds[k].z], (unsigned long long)(nz * SCALE));
        atomicAdd(&s_acc[ds[k].w], (unsigned long long)(nw * SCALE));
    }
    __syncthreads();

    const float w = gcn_w[0], b = gcn_b[0];
    for (int n = tid; n < NN; n += 256) {
        float di = s_emb[n];
        float agg = (float)((double)s_acc[n] * 0x1p-40) + di * di;
        s_emb[n] = agg * w + b;       // in-place: dinv dead after this
    }
    __syncthreads();

    // --- fold: thread (cg, seg): cols [cg*4, cg*4+4), nodes [seg*256, +256) ---
    {
        const int cg = tid & 31, seg = tid >> 5;
        const int c4 = cg * 4;
        const int nbase = seg * 256;
        float4 acc = make_float4(0.f, 0.f, 0.f, 0.f);
        #pragma unroll 4
        for (int i = 0; i < 256; i += 4) {
            float4 e = *(const float4*)&s_emb[nbase + i];   // broadcast b128
            float4 w0 = *(const float4*)&emb_W[(size_t)(nbase + i + 0) * NOISE + c4];
            float4 w1 = *(const float4*)&emb_W[(size_t)(nbase + i + 1) * NOISE + c4];
            float4 w2 = *(const float4*)&emb_W[(size_t)(nbase + i + 2) * NOISE + c4];
            float4 w3 = *(const float4*)&emb_W[(size_t)(nbase + i + 3) * NOISE + c4];
            acc.x = fmaf(e.x, w0.x, acc.x); acc.y = fmaf(e.x, w0.y, acc.y);
            acc.z = fmaf(e.x, w0.z, acc.z); acc.w = fmaf(e.x, w0.w, acc.w);
            acc.x = fmaf(e.y, w1.x, acc.x); acc.y = fmaf(e.y, w1.y, acc.y);
            acc.z = fmaf(e.y, w1.z, acc.z); acc.w = fmaf(e.y, w1.w, acc.w);
            acc.x = fmaf(e.z, w2.x, acc.x); acc.y = fmaf(e.z, w2.y, acc.y);
            acc.z = fmaf(e.z, w2.z, acc.z); acc.w = fmaf(e.z, w2.w, acc.w);
            acc.x = fmaf(e.w, w3.x, acc.x); acc.y = fmaf(e.w, w3.y, acc.y);
            acc.z = fmaf(e.w, w3.z, acc.z); acc.w = fmaf(e.w, w3.w, acc.w);
        }
        *(float4*)&s_part[seg][c4] = acc;
    }
    __syncthreads();
    if (tid < NOISE) {
        float s = 0.f;
        #pragma unroll
        for (int k = 0; k < 8; ++k) s += s_part[k][tid];
        graph_out[g * NOISE + tid] = s;
    }
}

// ---------------------------------------------------------------------------
// Kernel C: main batched kernel. 32 rows/block, 2 barriers.
// Phase 1: (2 cols {j,j+16} x 2 rows)/thread, bank-spread strides.
// Phase 2: 4 cols x 4 rows per thread (w2/w3 as float4 regs) — halves the
// per-row trig broadcast count vs 2-col; row metadata via LDS broadcasts.
// ---------------------------------------------------------------------------
#define ROWS 32
__global__ __launch_bounds__(256, 2) void main_kernel(
    const int* __restrict__ bg,          // [B]
    const float* __restrict__ chain,     // [B]
    const float* __restrict__ trig_in,   // [B,64]
    const float* __restrict__ txs,       // [B,8]
    const float* __restrict__ trig_W,    // [64,32]
    const float* __restrict__ trig_b,    // [32]
    const float* __restrict__ emb_W,     // [2089,128]
    const float* __restrict__ emb_b,     // [128]
    const float* __restrict__ graph_out, // [64,128]
    float* __restrict__ out)             // [B,128]
{
    __shared__ float s_td[ROWS * 68];    // trigger rows, stride 68 (8.7 KB)
    __shared__ float s_twT[32 * 68];     // trig_W^T [j][i], stride 68 (8.7 KB)
    __shared__ float s_trig[ROWS * 36];  // relu'd trig, stride 36 (4.6 KB)
    __shared__ float s_tx[ROWS * TXD];   // 1 KB
    __shared__ float s_ch[ROWS];
    __shared__ int   s_gi[ROWS];

    const int tid = threadIdx.x;
    const int row0 = blockIdx.x * ROWS;

    // --- stage trigger rows: 32x64 floats = 512 float4 ---
    {
        const float4* __restrict__ gsrc =
            (const float4*)(trig_in + (size_t)row0 * META);
        #pragma unroll
        for (int k = 0; k < 2; ++k) {
            int t = tid + k * 256;
            int r = t >> 4, i4 = t & 15;
            *(float4*)&s_td[r * 68 + i4 * 4] = gsrc[t];
        }
    }
    // --- stage trig_W transposed: 512 float4, scatter ---
    {
        const float4* __restrict__ gsrc = (const float4*)trig_W;
        #pragma unroll
        for (int k = 0; k < 2; ++k) {
            int t = tid + k * 256;
            int i = t >> 3, j4 = (t & 7) * 4;
            float4 v = gsrc[t];
            s_twT[(j4 + 0) * 68 + i] = v.x;
            s_twT[(j4 + 1) * 68 + i] = v.y;
            s_twT[(j4 + 2) * 68 + i] = v.z;
            s_twT[(j4 + 3) * 68 + i] = v.w;
        }
    }
    // --- stage row metadata: tx (64 float4), chain, graph idx ---
    if (tid < 64) {
        int r = tid >> 1, k4 = (tid & 1) * 4;
        *(float4*)&s_tx[r * TXD + k4] =
            ((const float4*)(txs + (size_t)row0 * TXD))[tid];
    } else if (tid < 96) {
        int r = tid - 64;
        s_ch[r] = chain[row0 + r];
    } else if (tid < 128) {
        int r = tid - 96;
        s_gi[r] = bg[row0 + r];
    }

    // --- per-thread 4-column weights (overlap with staging latency) ---
    const int n0 = (tid & 31) * 4;
    float4 w2[32], w3[TXD];
    #pragma unroll
    for (int j = 0; j < 32; ++j)
        w2[j] = *(const float4*)&emb_W[(size_t)(2049 + j) * NOISE + n0];
    #pragma unroll
    for (int k = 0; k < TXD; ++k)
        w3[k] = *(const float4*)&emb_W[(size_t)(2081 + k) * NOISE + n0];
    const float4 w1   = *(const float4*)&emb_W[(size_t)2048 * NOISE + n0];
    const float4 bias = *(const float4*)&emb_b[n0];

    __syncthreads();

    // --- phase 1: trig = relu(td @ trig_W + b); cols {j0, j0+16} x 2 rows ---
    {
        const int j0 = tid & 15;
        const int r0 = (tid >> 4) * 2;
        const float* __restrict__ tw0 = s_twT + j0 * 68;
        const float* __restrict__ tw1 = s_twT + (j0 + 16) * 68;
        const float* __restrict__ td0 = s_td + r0 * 68;
        const float* __restrict__ td1 = s_td + (r0 + 1) * 68;
        float b0 = trig_b[j0], b1 = trig_b[j0 + 16];
        float a00 = b0, a01 = b1, a10 = b0, a11 = b1;
        #pragma unroll
        for (int i = 0; i < META; i += 4) {
            float4 u0 = *(const float4*)(tw0 + i);
            float4 u1 = *(const float4*)(tw1 + i);
            float4 t0 = *(const float4*)(td0 + i);
            float4 t1 = *(const float4*)(td1 + i);
            a00 = fmaf(t0.x, u0.x, a00); a00 = fmaf(t0.y, u0.y, a00);
            a00 = fmaf(t0.z, u0.z, a00); a00 = fmaf(t0.w, u0.w, a00);
            a01 = fmaf(t0.x, u1.x, a01); a01 = fmaf(t0.y, u1.y, a01);
            a01 = fmaf(t0.z, u1.z, a01); a01 = fmaf(t0.w, u1.w, a01);
            a10 = fmaf(t1.x, u0.x, a10); a10 = fmaf(t1.y, u0.y, a10);
            a10 = fmaf(t1.z, u0.z, a10); a10 = fmaf(t1.w, u0.w, a10);
            a11 = fmaf(t1.x, u1.x, a11); a11 = fmaf(t1.y, u1.y, a11);
            a11 = fmaf(t1.z, u1.z, a11); a11 = fmaf(t1.w, u1.w, a11);
        }
        s_trig[r0 * 36 + j0]            = fmaxf(a00, 0.f);
        s_trig[r0 * 36 + j0 + 16]       = fmaxf(a01, 0.f);
        s_trig[(r0 + 1) * 36 + j0]      = fmaxf(a10, 0.f);
        s_trig[(r0 + 1) * 36 + j0 + 16] = fmaxf(a11, 0.f);
    }
    __syncthreads();

    // --- phase 2: 4 rows x 4 cols per thread ---
    const int rg = tid >> 5;   // 0..7: row subgroup (2 distinct rows per wave)
    int   gs[4];
    float chs[4];
    #pragma unroll
    for (int p = 0; p < 4; ++p) {
        const int r = p * 8 + rg;
        gs[p]  = s_gi[r];
        chs[p] = s_ch[r];
    }
    float4 go[4];
    #pragma unroll
    for (int p = 0; p < 4; ++p)
        go[p] = *(const float4*)&graph_out[gs[p] * NOISE + n0];

    #pragma unroll
    for (int p = 0; p < 4; ++p) {
        const int r = p * 8 + rg;
        const int row = row0 + r;
        float ax = bias.x + go[p].x + chs[p] * w1.x;
        float ay = bias.y + go[p].y + chs[p] * w1.y;
        float az = bias.z + go[p].z + chs[p] * w1.z;
        float aw = bias.w + go[p].w + chs[p] * w1.w;
        const float4* __restrict__ tx4 = (const float4*)(s_tx + r * TXD);
        float4 t0 = tx4[0], t1 = tx4[1];
        ax = fmaf(t0.x, w3[0].x, ax); ay = fmaf(t0.x, w3[0].y, ay);
        az = fmaf(t0.x, w3[0].z, az); aw = fmaf(t0.x, w3[0].w, aw);
        ax = fmaf(t0.y, w3[1].x, ax); ay = fmaf(t0.y, w3[1].y, ay);
        az = fmaf(t0.y, w3[1].z, az); aw = fmaf(t0.y, w3[1].w, aw);
        ax = fmaf(t0.z, w3[2].x, ax); ay = fmaf(t0.z, w3[2].y, ay);
        az = fmaf(t0.z, w3[2].z, az); aw = fmaf(t0.z, w3[2].w, aw);
        ax = fmaf(t0.w, w3[3].x, ax); ay = fmaf(t0.w, w3[3].y, ay);
        az = fmaf(t0.w, w3[3].z, az); aw = fmaf(t0.w, w3[3].w, aw);
        ax = fmaf(t1.x, w3[4].x, ax); ay = fmaf(t1.x, w3[4].y, ay);
        az = fmaf(t1.x, w3[4].z, az); aw = fmaf(t1.x, w3[4].w, aw);
        ax = fmaf(t1.y, w3[5].x, ax); ay = fmaf(t1.y, w3[5].y, ay);
        az = fmaf(t1.y, w3[5].z, az); aw = fmaf(t1.y, w3[5].w, aw);
        ax = fmaf(t1.z, w3[6].x, ax); ay = fmaf(t1.z, w3[6].y, ay);
        az = fmaf(t1.z, w3[6].z, az); aw = fmaf(t1.z, w3[6].w, aw);
        ax = fmaf(t1.w, w3[7].x, ax); ay = fmaf(t1.w, w3[7].y, ay);
        az = fmaf(t1.w, w3[7].z, az); aw = fmaf(t1.w, w3[7].w, aw);
        const float* __restrict__ tg = s_trig + r * 36;
        #pragma unroll
        for (int q = 0; q < 8; ++q) {
            float4 t4 = *(const float4*)(tg + q * 4);   // ~2-way broadcast
            ax = fmaf(t4.x, w2[4 * q + 0].x, ax); ay = fmaf(t4.x, w2[4 * q + 0].y, ay);
            az = fmaf(t4.x, w2[4 * q + 0].z, az); aw = fmaf(t4.x, w2[4 * q + 0].w, aw);
            ax = fmaf(t4.y, w2[4 * q + 1].x, ax); ay = fmaf(t4.y, w2[4 * q + 1].y, ay);
            az = fmaf(t4.y, w2[4 * q + 1].z, az); aw = fmaf(t4.y, w2[4 * q + 1].w, aw);
            ax = fmaf(t4.z, w2[4 * q + 2].x, ax); ay = fmaf(t4.z, w2[4 * q + 2].y, ay);
            az = fmaf(t4.z, w2[4 * q + 2].z, az); aw = fmaf(t4.z, w2[4 * q + 2].w, aw);
            ax = fmaf(t4.w, w2[4 * q + 3].x, ax); ay = fmaf(t4.w, w2[4 * q + 3].y, ay);
            az = fmaf(t4.w, w2[4 * q + 3].z, az); aw = fmaf(t4.w, w2[4 * q + 3].w, aw);
        }
        *(float4*)&out[(size_t)row * NOISE + n0] = make_float4(ax, ay, az, aw);
    }
}

extern "C" void kernel_launch(void* const* d_in, const int* in_sizes, int n_in,
                              void* d_out, int out_size, void* d_ws, size_t ws_size,
                              hipStream_t stream) {
    const int*   bg      = (const int*)d_in[0];
    const float* chain   = (const float*)d_in[1];
    const float* trig_in = (const float*)d_in[2];
    const float* txs     = (const float*)d_in[3];
    const int*   edges   = (const int*)d_in[4];
    const float* gcn_w   = (const float*)d_in[5];
    const float* gcn_b   = (const float*)d_in[6];
    const float* trig_W  = (const float*)d_in[7];
    const float* trig_b  = (const float*)d_in[8];
    const float* emb_W   = (const float*)d_in[9];
    const float* emb_b   = (const float*)d_in[10];
    float* out = (float*)d_out;

    float* graph_out = (float*)d_ws;   // 64*128 floats = 32 KB

    agg_fold_kernel<<<NG, 256, 0, stream>>>(edges, gcn_w, gcn_b, emb_W, graph_out);
    main_kernel<<<BB / ROWS, 256, 0, stream>>>(bg, chain, trig_in, txs, trig_W,
                                               trig_b, emb_W, emb_b, graph_out, out);
}

// Round 8
// 132.858 us; speedup vs baseline: 1.0436x; 1.0436x over previous
//
#include <hip/hip_runtime.h>

#define NN 2048     // nodes per graph
#define NG 64       // graphs
#define NE 16384    // edges per graph
#define BB 65536    // batch
#define META 64
#define TXD 8
#define NOISE 128

// ws layout:
//   [0, 32KB)      graph_out [64][128]
//   [32KB, 544KB)  emb       [64][2048]

// ---------------------------------------------------------------------------
// Kernel A: per-graph GCN aggregation -> emb[g][n]. One block per graph.
// Native int LDS atomics for deg; u64 fixed-point (x 2^40) for agg.
// Also zeroes graph_out[g][:] for fold's atomics.
// ---------------------------------------------------------------------------
__global__ __launch_bounds__(256) void agg_kernel(
    const int* __restrict__ edges,     // [64,2,16384]
    const float* __restrict__ gcn_w,
    const float* __restrict__ gcn_b,
    float* __restrict__ emb,           // [64,2048] (ws)
    float* __restrict__ graph_out)     // [64,128]  (ws, zeroed here)
{
    __shared__ int                s_cnt[NN];    // 8 KB
    __shared__ float              s_dinv[NN];   // 8 KB
    __shared__ unsigned long long s_acc[NN];    // 16 KB
    const int g = blockIdx.x, tid = threadIdx.x;
    const int4* __restrict__ e4 = (const int4*)(edges + (size_t)g * 2 * NE);

    if (tid < NOISE) graph_out[g * NOISE + tid] = 0.0f;

    int4 ds[16];
    #pragma unroll
    for (int k = 0; k < 16; ++k) ds[k] = e4[4096 + k * 256 + tid];

    for (int n = tid; n < NN; n += 256) { s_cnt[n] = 1; s_acc[n] = 0ull; }
    __syncthreads();

    #pragma unroll
    for (int k = 0; k < 16; ++k) {
        atomicAdd(&s_cnt[ds[k].x], 1);
        atomicAdd(&s_cnt[ds[k].y], 1);
        atomicAdd(&s_cnt[ds[k].z], 1);
        atomicAdd(&s_cnt[ds[k].w], 1);
    }
    __syncthreads();
    for (int n = tid; n < NN; n += 256) s_dinv[n] = rsqrtf((float)s_cnt[n]);
    __syncthreads();

    const float SCALE = 1099511627776.0f;  // 2^40
    #pragma unroll
    for (int k = 0; k < 16; ++k) {
        int4 sr = e4[k * 256 + tid];
        float nx = s_dinv[sr.x] * s_dinv[ds[k].x];
        float ny = s_dinv[sr.y] * s_dinv[ds[k].y];
        float nz = s_dinv[sr.z] * s_dinv[ds[k].z];
        float nw = s_dinv[sr.w] * s_dinv[ds[k].w];
        atomicAdd(&s_acc[ds[k].x], (unsigned long long)(nx * SCALE));
        atomicAdd(&s_acc[ds[k].y], (unsigned long long)(ny * SCALE));
        atomicAdd(&s_acc[ds[k].z], (unsigned long long)(nz * SCALE));
        atomicAdd(&s_acc[ds[k].w], (unsigned long long)(nw * SCALE));
    }
    __syncthreads();

    const float w = gcn_w[0], b = gcn_b[0];
    for (int n = tid; n < NN; n += 256) {
        float di = s_dinv[n];
        float agg = (float)((double)s_acc[n] * 0x1p-40) + di * di;
        emb[(size_t)g * NN + n] = agg * w + b;
    }
}

// ---------------------------------------------------------------------------
// Kernel B: fold emb @ emb_W[0:2048] -> graph_out[64][128].
// 1024 blocks = 64 graphs x 16 node-chunks of 128; LDS-reduce then atomic.
// ---------------------------------------------------------------------------
__global__ __launch_bounds__(256) void fold_kernel(
    const float* __restrict__ emb,       // [64,2048]
    const float* __restrict__ emb_W,     // [2089,128]
    float* __restrict__ graph_out)       // [64,128], zeroed by agg_kernel
{
    __shared__ float s_e[128];
    __shared__ float s_red[128];
    const int tid = threadIdx.x;
    const int g = blockIdx.x >> 4, chunk = blockIdx.x & 15;
    const int n0 = chunk * 128;
    if (tid < 128) s_e[tid] = emb[(size_t)g * NN + n0 + tid];
    __syncthreads();
    const int c = tid & 127, h = tid >> 7;
    const float* __restrict__ Wp = emb_W + (size_t)(n0 + h * 64) * NOISE + c;
    const float* __restrict__ ep = s_e + h * 64;
    float a0 = 0.f, a1 = 0.f, a2 = 0.f, a3 = 0.f;
    #pragma unroll
    for (int i = 0; i < 64; i += 4) {
        a0 = fmaf(ep[i + 0], Wp[(i + 0) * NOISE], a0);
        a1 = fmaf(ep[i + 1], Wp[(i + 1) * NOISE], a1);
        a2 = fmaf(ep[i + 2], Wp[(i + 2) * NOISE], a2);
        a3 = fmaf(ep[i + 3], Wp[(i + 3) * NOISE], a3);
    }
    float acc = (a0 + a1) + (a2 + a3);
    if (h == 1) s_red[c] = acc;
    __syncthreads();
    if (h == 0) atomicAdd(&graph_out[g * NOISE + c], acc + s_red[c]);
}

// ---------------------------------------------------------------------------
// Kernel C: main batched kernel. 32 rows/block, 2 barriers.
// Phase 1: (2 cols {j,j+16} x 2 rows)/thread, bank-spread strides.
// Phase 2: 4 cols x 4 rows per thread (w2/w3 as float4 regs) — halves the
// per-row trig broadcast count vs 2-col; row metadata via LDS broadcasts.
// ---------------------------------------------------------------------------
#define ROWS 32
__global__ __launch_bounds__(256, 2) void main_kernel(
    const int* __restrict__ bg,          // [B]
    const float* __restrict__ chain,     // [B]
    const float* __restrict__ trig_in,   // [B,64]
    const float* __restrict__ txs,       // [B,8]
    const float* __restrict__ trig_W,    // [64,32]
    const float* __restrict__ trig_b,    // [32]
    const float* __restrict__ emb_W,     // [2089,128]
    const float* __restrict__ emb_b,     // [128]
    const float* __restrict__ graph_out, // [64,128]
    float* __restrict__ out)             // [B,128]
{
    __shared__ float s_td[ROWS * 68];    // trigger rows, stride 68 (8.7 KB)
    __shared__ float s_twT[32 * 68];     // trig_W^T [j][i], stride 68 (8.7 KB)
    __shared__ float s_trig[ROWS * 36];  // relu'd trig, stride 36 (4.6 KB)
    __shared__ float s_tx[ROWS * TXD];   // 1 KB
    __shared__ float s_ch[ROWS];
    __shared__ int   s_gi[ROWS];

    const int tid = threadIdx.x;
    const int row0 = blockIdx.x * ROWS;

    // --- stage trigger rows: 32x64 floats = 512 float4 ---
    {
        const float4* __restrict__ gsrc =
            (const float4*)(trig_in + (size_t)row0 * META);
        #pragma unroll
        for (int k = 0; k < 2; ++k) {
            int t = tid + k * 256;
            int r = t >> 4, i4 = t & 15;
            *(float4*)&s_td[r * 68 + i4 * 4] = gsrc[t];
        }
    }
    // --- stage trig_W transposed: 512 float4, scatter ---
    {
        const float4* __restrict__ gsrc = (const float4*)trig_W;
        #pragma unroll
        for (int k = 0; k < 2; ++k) {
            int t = tid + k * 256;
            int i = t >> 3, j4 = (t & 7) * 4;
            float4 v = gsrc[t];
            s_twT[(j4 + 0) * 68 + i] = v.x;
            s_twT[(j4 + 1) * 68 + i] = v.y;
            s_twT[(j4 + 2) * 68 + i] = v.z;
            s_twT[(j4 + 3) * 68 + i] = v.w;
        }
    }
    // --- stage row metadata: tx (64 float4), chain, graph idx ---
    if (tid < 64) {
        int r = tid >> 1, k4 = (tid & 1) * 4;
        *(float4*)&s_tx[r * TXD + k4] =
            ((const float4*)(txs + (size_t)row0 * TXD))[tid];
    } else if (tid < 96) {
        int r = tid - 64;
        s_ch[r] = chain[row0 + r];
    } else if (tid < 128) {
        int r = tid - 96;
        s_gi[r] = bg[row0 + r];
    }

    // --- per-thread 4-column weights (overlap with staging latency) ---
    const int n0 = (tid & 31) * 4;
    float4 w2[32], w3[TXD];
    #pragma unroll
    for (int j = 0; j < 32; ++j)
        w2[j] = *(const float4*)&emb_W[(size_t)(2049 + j) * NOISE + n0];
    #pragma unroll
    for (int k = 0; k < TXD; ++k)
        w3[k] = *(const float4*)&emb_W[(size_t)(2081 + k) * NOISE + n0];
    const float4 w1   = *(const float4*)&emb_W[(size_t)2048 * NOISE + n0];
    const float4 bias = *(const float4*)&emb_b[n0];

    __syncthreads();

    // --- phase 1: trig = relu(td @ trig_W + b); cols {j0, j0+16} x 2 rows ---
    {
        const int j0 = tid & 15;
        const int r0 = (tid >> 4) * 2;
        const float* __restrict__ tw0 = s_twT + j0 * 68;
        const float* __restrict__ tw1 = s_twT + (j0 + 16) * 68;
        const float* __restrict__ td0 = s_td + r0 * 68;
        const float* __restrict__ td1 = s_td + (r0 + 1) * 68;
        float b0 = trig_b[j0], b1 = trig_b[j0 + 16];
        float a00 = b0, a01 = b1, a10 = b0, a11 = b1;
        #pragma unroll
        for (int i = 0; i < META; i += 4) {
            float4 u0 = *(const float4*)(tw0 + i);
            float4 u1 = *(const float4*)(tw1 + i);
            float4 t0 = *(const float4*)(td0 + i);
            float4 t1 = *(const float4*)(td1 + i);
            a00 = fmaf(t0.x, u0.x, a00); a00 = fmaf(t0.y, u0.y, a00);
            a00 = fmaf(t0.z, u0.z, a00); a00 = fmaf(t0.w, u0.w, a00);
            a01 = fmaf(t0.x, u1.x, a01); a01 = fmaf(t0.y, u1.y, a01);
            a01 = fmaf(t0.z, u1.z, a01); a01 = fmaf(t0.w, u1.w, a01);
            a10 = fmaf(t1.x, u0.x, a10); a10 = fmaf(t1.y, u0.y, a10);
            a10 = fmaf(t1.z, u0.z, a10); a10 = fmaf(t1.w, u0.w, a10);
            a11 = fmaf(t1.x, u1.x, a11); a11 = fmaf(t1.y, u1.y, a11);
            a11 = fmaf(t1.z, u1.z, a11); a11 = fmaf(t1.w, u1.w, a11);
        }
        s_trig[r0 * 36 + j0]            = fmaxf(a00, 0.f);
        s_trig[r0 * 36 + j0 + 16]       = fmaxf(a01, 0.f);
        s_trig[(r0 + 1) * 36 + j0]      = fmaxf(a10, 0.f);
        s_trig[(r0 + 1) * 36 + j0 + 16] = fmaxf(a11, 0.f);
    }
    __syncthreads();

    // --- phase 2: 4 rows x 4 cols per thread ---
    const int rg = tid >> 5;   // 0..7: row subgroup (2 distinct rows per wave)
    int   gs[4];
    float chs[4];
    #pragma unroll
    for (int p = 0; p < 4; ++p) {
        const int r = p * 8 + rg;
        gs[p]  = s_gi[r];
        chs[p] = s_ch[r];
    }
    float4 go[4];
    #pragma unroll
    for (int p = 0; p < 4; ++p)
        go[p] = *(const float4*)&graph_out[gs[p] * NOISE + n0];

    #pragma unroll
    for (int p = 0; p < 4; ++p) {
        const int r = p * 8 + rg;
        const int row = row0 + r;
        float ax = bias.x + go[p].x + chs[p] * w1.x;
        float ay = bias.y + go[p].y + chs[p] * w1.y;
        float az = bias.z + go[p].z + chs[p] * w1.z;
        float aw = bias.w + go[p].w + chs[p] * w1.w;
        const float4* __restrict__ tx4 = (const float4*)(s_tx + r * TXD);
        float4 t0 = tx4[0], t1 = tx4[1];
        ax = fmaf(t0.x, w3[0].x, ax); ay = fmaf(t0.x, w3[0].y, ay);
        az = fmaf(t0.x, w3[0].z, az); aw = fmaf(t0.x, w3[0].w, aw);
        ax = fmaf(t0.y, w3[1].x, ax); ay = fmaf(t0.y, w3[1].y, ay);
        az = fmaf(t0.y, w3[1].z, az); aw = fmaf(t0.y, w3[1].w, aw);
        ax = fmaf(t0.z, w3[2].x, ax); ay = fmaf(t0.z, w3[2].y, ay);
        az = fmaf(t0.z, w3[2].z, az); aw = fmaf(t0.z, w3[2].w, aw);
        ax = fmaf(t0.w, w3[3].x, ax); ay = fmaf(t0.w, w3[3].y, ay);
        az = fmaf(t0.w, w3[3].z, az); aw = fmaf(t0.w, w3[3].w, aw);
        ax = fmaf(t1.x, w3[4].x, ax); ay = fmaf(t1.x, w3[4].y, ay);
        az = fmaf(t1.x, w3[4].z, az); aw = fmaf(t1.x, w3[4].w, aw);
        ax = fmaf(t1.y, w3[5].x, ax); ay = fmaf(t1.y, w3[5].y, ay);
        az = fmaf(t1.y, w3[5].z, az); aw = fmaf(t1.y, w3[5].w, aw);
        ax = fmaf(t1.z, w3[6].x, ax); ay = fmaf(t1.z, w3[6].y, ay);
        az = fmaf(t1.z, w3[6].z, az); aw = fmaf(t1.z, w3[6].w, aw);
        ax = fmaf(t1.w, w3[7].x, ax); ay = fmaf(t1.w, w3[7].y, ay);
        az = fmaf(t1.w, w3[7].z, az); aw = fmaf(t1.w, w3[7].w, aw);
        const float* __restrict__ tg = s_trig + r * 36;
        #pragma unroll
        for (int q = 0; q < 8; ++q) {
            float4 t4 = *(const float4*)(tg + q * 4);   // ~2-way broadcast
            ax = fmaf(t4.x, w2[4 * q + 0].x, ax); ay = fmaf(t4.x, w2[4 * q + 0].y, ay);
            az = fmaf(t4.x, w2[4 * q + 0].z, az); aw = fmaf(t4.x, w2[4 * q + 0].w, aw);
            ax = fmaf(t4.y, w2[4 * q + 1].x, ax); ay = fmaf(t4.y, w2[4 * q + 1].y, ay);
            az = fmaf(t4.y, w2[4 * q + 1].z, az); aw = fmaf(t4.y, w2[4 * q + 1].w, aw);
            ax = fmaf(t4.z, w2[4 * q + 2].x, ax); ay = fmaf(t4.z, w2[4 * q + 2].y, ay);
            az = fmaf(t4.z, w2[4 * q + 2].z, az); aw = fmaf(t4.z, w2[4 * q + 2].w, aw);
            ax = fmaf(t4.w, w2[4 * q + 3].x, ax); ay = fmaf(t4.w, w2[4 * q + 3].y, ay);
            az = fmaf(t4.w, w2[4 * q + 3].z, az); aw = fmaf(t4.w, w2[4 * q + 3].w, aw);
        }
        *(float4*)&out[(size_t)row * NOISE + n0] = make_float4(ax, ay, az, aw);
    }
}

extern "C" void kernel_launch(void* const* d_in, const int* in_sizes, int n_in,
                              void* d_out, int out_size, void* d_ws, size_t ws_size,
                              hipStream_t stream) {
    const int*   bg      = (const int*)d_in[0];
    const float* chain   = (const float*)d_in[1];
    const float* trig_in = (const float*)d_in[2];
    const float* txs     = (const float*)d_in[3];
    const int*   edges   = (const int*)d_in[4];
    const float* gcn_w   = (const float*)d_in[5];
    const float* gcn_b   = (const float*)d_in[6];
    const float* trig_W  = (const float*)d_in[7];
    const float* trig_b  = (const float*)d_in[8];
    const float* emb_W   = (const float*)d_in[9];
    const float* emb_b   = (const float*)d_in[10];
    float* out = (float*)d_out;

    float* graph_out = (float*)d_ws;                 // 64*128 floats = 32 KB
    float* emb       = (float*)d_ws + NG * NOISE;    // 64*2048 floats = 512 KB

    agg_kernel<<<NG, 256, 0, stream>>>(edges, gcn_w, gcn_b, emb, graph_out);
    fold_kernel<<<NG * 16, 256, 0, stream>>>(emb, emb_W, graph_out);
    main_kernel<<<BB / ROWS, 256, 0, stream>>>(bg, chain, trig_in, txs, trig_W,
                                               trig_b, emb_W, emb_b, graph_out, out);
}

// Round 9
// 131.335 us; speedup vs baseline: 1.0557x; 1.0116x over previous
//
#include <hip/hip_runtime.h>

#define NN 2048     // nodes per graph
#define NG 64       // graphs
#define NE 16384    // edges per graph
#define BB 65536    // batch
#define META 64
#define TXD 8
#define NOISE 128

// ws layout:
//   [0, 32KB)        graph_out [64][128]
//   [32KB, 544KB)    emb       [64][2048]
//   [544KB, 548KB)   prefetch dummy sink [1024] int

// ---------------------------------------------------------------------------
// Kernel P: XCD-aware L2 prefetch of edges. Block j reads graph (j&63)'s
// chunk (j>>6); round-robin block->XCD gives (j%8)==(graph%8), matching the
// XCD that agg block g will run on. Reduction + dummy store prevent DCE.
// ---------------------------------------------------------------------------
__global__ __launch_bounds__(256) void prefetch_kernel(
    const int* __restrict__ edges,   // [64,2,16384]
    int* __restrict__ sink)          // [1024] (ws)
{
    const int j = blockIdx.x;
    const int b = j & 63, a = j >> 6;
    const int4* __restrict__ p =
        (const int4*)(edges + (size_t)b * 2 * NE) + a * 512;
    int4 v0 = p[threadIdx.x];
    int4 v1 = p[threadIdx.x + 256];
    int s = v0.x + v0.y + v0.z + v0.w + v1.x + v1.y + v1.z + v1.w;
    __shared__ int red;
    if (threadIdx.x == 0) red = 0;
    __syncthreads();
    atomicAdd(&red, s);
    __syncthreads();
    if (threadIdx.x == 0) sink[j] = red;
}

// ---------------------------------------------------------------------------
// Kernel A: per-graph GCN aggregation -> emb[g][n]. One block per graph.
// Native int LDS atomics for deg; u64 fixed-point (x 2^40) for agg.
// Also zeroes graph_out[g][:] for fold's atomics.
// ---------------------------------------------------------------------------
__global__ __launch_bounds__(256) void agg_kernel(
    const int* __restrict__ edges,     // [64,2,16384]
    const float* __restrict__ gcn_w,
    const float* __restrict__ gcn_b,
    float* __restrict__ emb,           // [64,2048] (ws)
    float* __restrict__ graph_out)     // [64,128]  (ws, zeroed here)
{
    __shared__ int                s_cnt[NN];    // 8 KB
    __shared__ float              s_dinv[NN];   // 8 KB
    __shared__ unsigned long long s_acc[NN];    // 16 KB
    const int g = blockIdx.x, tid = threadIdx.x;
    const int4* __restrict__ e4 = (const int4*)(edges + (size_t)g * 2 * NE);

    if (tid < NOISE) graph_out[g * NOISE + tid] = 0.0f;

    int4 ds[16];
    #pragma unroll
    for (int k = 0; k < 16; ++k) ds[k] = e4[4096 + k * 256 + tid];

    for (int n = tid; n < NN; n += 256) { s_cnt[n] = 1; s_acc[n] = 0ull; }
    __syncthreads();

    #pragma unroll
    for (int k = 0; k < 16; ++k) {
        atomicAdd(&s_cnt[ds[k].x], 1);
        atomicAdd(&s_cnt[ds[k].y], 1);
        atomicAdd(&s_cnt[ds[k].z], 1);
        atomicAdd(&s_cnt[ds[k].w], 1);
    }
    __syncthreads();
    for (int n = tid; n < NN; n += 256) s_dinv[n] = rsqrtf((float)s_cnt[n]);
    __syncthreads();

    const float SCALE = 1099511627776.0f;  // 2^40
    #pragma unroll
    for (int k = 0; k < 16; ++k) {
        int4 sr = e4[k * 256 + tid];
        float nx = s_dinv[sr.x] * s_dinv[ds[k].x];
        float ny = s_dinv[sr.y] * s_dinv[ds[k].y];
        float nz = s_dinv[sr.z] * s_dinv[ds[k].z];
        float nw = s_dinv[sr.w] * s_dinv[ds[k].w];
        atomicAdd(&s_acc[ds[k].x], (unsigned long long)(nx * SCALE));
        atomicAdd(&s_acc[ds[k].y], (unsigned long long)(ny * SCALE));
        atomicAdd(&s_acc[ds[k].z], (unsigned long long)(nz * SCALE));
        atomicAdd(&s_acc[ds[k].w], (unsigned long long)(nw * SCALE));
    }
    __syncthreads();

    const float w = gcn_w[0], b = gcn_b[0];
    for (int n = tid; n < NN; n += 256) {
        float di = s_dinv[n];
        float agg = (float)((double)s_acc[n] * 0x1p-40) + di * di;
        emb[(size_t)g * NN + n] = agg * w + b;
    }
}

// ---------------------------------------------------------------------------
// Kernel B: fold emb @ emb_W[0:2048] -> graph_out[64][128].
// 1024 blocks = 64 graphs x 16 node-chunks of 128; LDS-reduce then atomic.
// ---------------------------------------------------------------------------
__global__ __launch_bounds__(256) void fold_kernel(
    const float* __restrict__ emb,       // [64,2048]
    const float* __restrict__ emb_W,     // [2089,128]
    float* __restrict__ graph_out)       // [64,128], zeroed by agg_kernel
{
    __shared__ float s_e[128];
    __shared__ float s_red[128];
    const int tid = threadIdx.x;
    const int g = blockIdx.x >> 4, chunk = blockIdx.x & 15;
    const int n0 = chunk * 128;
    if (tid < 128) s_e[tid] = emb[(size_t)g * NN + n0 + tid];
    __syncthreads();
    const int c = tid & 127, h = tid >> 7;
    const float* __restrict__ Wp = emb_W + (size_t)(n0 + h * 64) * NOISE + c;
    const float* __restrict__ ep = s_e + h * 64;
    float a0 = 0.f, a1 = 0.f, a2 = 0.f, a3 = 0.f;
    #pragma unroll
    for (int i = 0; i < 64; i += 4) {
        a0 = fmaf(ep[i + 0], Wp[(i + 0) * NOISE], a0);
        a1 = fmaf(ep[i + 1], Wp[(i + 1) * NOISE], a1);
        a2 = fmaf(ep[i + 2], Wp[(i + 2) * NOISE], a2);
        a3 = fmaf(ep[i + 3], Wp[(i + 3) * NOISE], a3);
    }
    float acc = (a0 + a1) + (a2 + a3);
    if (h == 1) s_red[c] = acc;
    __syncthreads();
    if (h == 0) atomicAdd(&graph_out[g * NOISE + c], acc + s_red[c]);
}

// ---------------------------------------------------------------------------
// Kernel C: main batched kernel (R6 best-known config). 32 rows/block.
// Phase 1: (2 cols {j,j+16} x 2 rows)/thread, bank-spread LDS strides.
// Phase 2: 2 cols/thread, row metadata from LDS broadcasts, graph_out
// gathers hoisted/batched for MLP.
// ---------------------------------------------------------------------------
#define ROWS 32
__global__ __launch_bounds__(256, 3) void main_kernel(
    const int* __restrict__ bg,          // [B]
    const float* __restrict__ chain,     // [B]
    const float* __restrict__ trig_in,   // [B,64]
    const float* __restrict__ txs,       // [B,8]
    const float* __restrict__ trig_W,    // [64,32]
    const float* __restrict__ trig_b,    // [32]
    const float* __restrict__ emb_W,     // [2089,128]
    const float* __restrict__ emb_b,     // [128]
    const float* __restrict__ graph_out, // [64,128]
    float* __restrict__ out)             // [B,128]
{
    __shared__ float s_td[ROWS * 68];    // trigger rows, stride 68 (8.7 KB)
    __shared__ float s_twT[32 * 68];     // trig_W^T [j][i], stride 68 (8.7 KB)
    __shared__ float s_trig[ROWS * 36];  // relu'd trig, stride 36 (4.6 KB)
    __shared__ float s_tx[ROWS * TXD];   // 1 KB
    __shared__ float s_ch[ROWS];
    __shared__ int   s_gi[ROWS];

    const int tid = threadIdx.x;
    const int row0 = blockIdx.x * ROWS;

    // --- stage trigger rows: 32x64 floats = 512 float4 ---
    {
        const float4* __restrict__ gsrc =
            (const float4*)(trig_in + (size_t)row0 * META);
        #pragma unroll
        for (int k = 0; k < 2; ++k) {
            int t = tid + k * 256;
            int r = t >> 4, i4 = t & 15;
            *(float4*)&s_td[r * 68 + i4 * 4] = gsrc[t];
        }
    }
    // --- stage trig_W transposed: 512 float4, scatter ---
    {
        const float4* __restrict__ gsrc = (const float4*)trig_W;
        #pragma unroll
        for (int k = 0; k < 2; ++k) {
            int t = tid + k * 256;
            int i = t >> 3, j4 = (t & 7) * 4;
            float4 v = gsrc[t];
            s_twT[(j4 + 0) * 68 + i] = v.x;
            s_twT[(j4 + 1) * 68 + i] = v.y;
            s_twT[(j4 + 2) * 68 + i] = v.z;
            s_twT[(j4 + 3) * 68 + i] = v.w;
        }
    }
    // --- stage row metadata: tx (64 float4), chain, graph idx ---
    if (tid < 64) {
        int r = tid >> 1, k4 = (tid & 1) * 4;
        *(float4*)&s_tx[r * TXD + k4] =
            ((const float4*)(txs + (size_t)row0 * TXD))[tid];
    } else if (tid < 96) {
        int r = tid - 64;
        s_ch[r] = chain[row0 + r];
    } else if (tid < 128) {
        int r = tid - 96;
        s_gi[r] = bg[row0 + r];
    }

    // --- per-thread column-pair weights (overlap with staging latency) ---
    const int n0 = (tid & 63) * 2;
    float2 w2[32], w3[TXD];
    #pragma unroll
    for (int j = 0; j < 32; ++j)
        w2[j] = *(const float2*)&emb_W[(size_t)(2049 + j) * NOISE + n0];
    #pragma unroll
    for (int k = 0; k < TXD; ++k)
        w3[k] = *(const float2*)&emb_W[(size_t)(2081 + k) * NOISE + n0];
    const float2 w1   = *(const float2*)&emb_W[(size_t)2048 * NOISE + n0];
    const float2 bias = *(const float2*)&emb_b[n0];

    __syncthreads();

    // --- phase 1: trig = relu(td @ trig_W + b); cols {j0, j0+16} x 2 rows ---
    {
        const int j0 = tid & 15;
        const int r0 = (tid >> 4) * 2;
        const float* __restrict__ tw0 = s_twT + j0 * 68;
        const float* __restrict__ tw1 = s_twT + (j0 + 16) * 68;
        const float* __restrict__ td0 = s_td + r0 * 68;
        const float* __restrict__ td1 = s_td + (r0 + 1) * 68;
        float b0 = trig_b[j0], b1 = trig_b[j0 + 16];
        float a00 = b0, a01 = b1, a10 = b0, a11 = b1;
        #pragma unroll
        for (int i = 0; i < META; i += 4) {
            float4 u0 = *(const float4*)(tw0 + i);
            float4 u1 = *(const float4*)(tw1 + i);
            float4 t0 = *(const float4*)(td0 + i);
            float4 t1 = *(const float4*)(td1 + i);
            a00 = fmaf(t0.x, u0.x, a00); a00 = fmaf(t0.y, u0.y, a00);
            a00 = fmaf(t0.z, u0.z, a00); a00 = fmaf(t0.w, u0.w, a00);
            a01 = fmaf(t0.x, u1.x, a01); a01 = fmaf(t0.y, u1.y, a01);
            a01 = fmaf(t0.z, u1.z, a01); a01 = fmaf(t0.w, u1.w, a01);
            a10 = fmaf(t1.x, u0.x, a10); a10 = fmaf(t1.y, u0.y, a10);
            a10 = fmaf(t1.z, u0.z, a10); a10 = fmaf(t1.w, u0.w, a10);
            a11 = fmaf(t1.x, u1.x, a11); a11 = fmaf(t1.y, u1.y, a11);
            a11 = fmaf(t1.z, u1.z, a11); a11 = fmaf(t1.w, u1.w, a11);
        }
        s_trig[r0 * 36 + j0]            = fmaxf(a00, 0.f);
        s_trig[r0 * 36 + j0 + 16]       = fmaxf(a01, 0.f);
        s_trig[(r0 + 1) * 36 + j0]      = fmaxf(a10, 0.f);
        s_trig[(r0 + 1) * 36 + j0 + 16] = fmaxf(a11, 0.f);
    }
    __syncthreads();

    // --- phase 2: 8 rows x 2 cols per thread ---
    const int wv = tid >> 6;   // rows wave-uniform -> LDS broadcasts
    int   gs[8];
    float chs[8];
    #pragma unroll
    for (int p = 0; p < 8; ++p) {
        const int r = p * 4 + wv;
        gs[p]  = s_gi[r];
        chs[p] = s_ch[r];
    }
    float2 go[8];
    #pragma unroll
    for (int p = 0; p < 8; ++p)
        go[p] = *(const float2*)&graph_out[gs[p] * NOISE + n0];

    #pragma unroll
    for (int p = 0; p < 8; ++p) {
        const int r = p * 4 + wv;
        const int row = row0 + r;
        float ax = bias.x + go[p].x + chs[p] * w1.x;
        float ay = bias.y + go[p].y + chs[p] * w1.y;
        const float4* __restrict__ tx4 = (const float4*)(s_tx + r * TXD);
        float4 t0 = tx4[0], t1 = tx4[1];
        ax = fmaf(t0.x, w3[0].x, ax); ay = fmaf(t0.x, w3[0].y, ay);
        ax = fmaf(t0.y, w3[1].x, ax); ay = fmaf(t0.y, w3[1].y, ay);
        ax = fmaf(t0.z, w3[2].x, ax); ay = fmaf(t0.z, w3[2].y, ay);
        ax = fmaf(t0.w, w3[3].x, ax); ay = fmaf(t0.w, w3[3].y, ay);
        ax = fmaf(t1.x, w3[4].x, ax); ay = fmaf(t1.x, w3[4].y, ay);
        ax = fmaf(t1.y, w3[5].x, ax); ay = fmaf(t1.y, w3[5].y, ay);
        ax = fmaf(t1.z, w3[6].x, ax); ay = fmaf(t1.z, w3[6].y, ay);
        ax = fmaf(t1.w, w3[7].x, ax); ay = fmaf(t1.w, w3[7].y, ay);
        const float* __restrict__ tg = s_trig + r * 36;
        #pragma unroll
        for (int q = 0; q < 8; ++q) {
            float4 t4 = *(const float4*)(tg + q * 4);   // broadcast b128
            ax = fmaf(t4.x, w2[4 * q + 0].x, ax); ay = fmaf(t4.x, w2[4 * q + 0].y, ay);
            ax = fmaf(t4.y, w2[4 * q + 1].x, ax); ay = fmaf(t4.y, w2[4 * q + 1].y, ay);
            ax = fmaf(t4.z, w2[4 * q + 2].x, ax); ay = fmaf(t4.z, w2[4 * q + 2].y, ay);
            ax = fmaf(t4.w, w2[4 * q + 3].x, ax); ay = fmaf(t4.w, w2[4 * q + 3].y, ay);
        }
        *(float2*)&out[(size_t)row * NOISE + n0] = make_float2(ax, ay);
    }
}

extern "C" void kernel_launch(void* const* d_in, const int* in_sizes, int n_in,
                              void* d_out, int out_size, void* d_ws, size_t ws_size,
                              hipStream_t stream) {
    const int*   bg      = (const int*)d_in[0];
    const float* chain   = (const float*)d_in[1];
    const float* trig_in = (const float*)d_in[2];
    const float* txs     = (const float*)d_in[3];
    const int*   edges   = (const int*)d_in[4];
    const float* gcn_w   = (const float*)d_in[5];
    const float* gcn_b   = (const float*)d_in[6];
    const float* trig_W  = (const float*)d_in[7];
    const float* trig_b  = (const float*)d_in[8];
    const float* emb_W   = (const float*)d_in[9];
    const float* emb_b   = (const float*)d_in[10];
    float* out = (float*)d_out;

    float* graph_out = (float*)d_ws;                 // 64*128 floats = 32 KB
    float* emb       = (float*)d_ws + NG * NOISE;    // 64*2048 floats = 512 KB
    int*   sink      = (int*)(emb + NG * NN);        // 1024 ints = 4 KB

    prefetch_kernel<<<1024, 256, 0, stream>>>(edges, sink);
    agg_kernel<<<NG, 256, 0, stream>>>(edges, gcn_w, gcn_b, emb, graph_out);
    fold_kernel<<<NG * 16, 256, 0, stream>>>(emb, emb_W, graph_out);
    main_kernel<<<BB / ROWS, 256, 0, stream>>>(bg, chain, trig_in, txs, trig_W,
                                               trig_b, emb_W, emb_b, graph_out, out);
}

// Round 10
// 130.295 us; speedup vs baseline: 1.0641x; 1.0080x over previous
//
#include <hip/hip_runtime.h>

#define NN 2048     // nodes per graph
#define NG 64       // graphs
#define NE 16384    // edges per graph
#define BB 65536    // batch
#define META 64
#define TXD 8
#define NOISE 128

// ws layout:
//   [0, 32KB)      graph_out [64][128]
//   [32KB, 544KB)  emb       [64][2048]

// ---------------------------------------------------------------------------
// Kernel A: per-graph GCN aggregation -> emb[g][n]. One block per graph.
// Native int LDS atomics for deg; u64 fixed-point (x 2^40) for agg.
// Also zeroes graph_out[g][:] for fold's atomics.
// ---------------------------------------------------------------------------
__global__ __launch_bounds__(256) void agg_kernel(
    const int* __restrict__ edges,     // [64,2,16384]
    const float* __restrict__ gcn_w,
    const float* __restrict__ gcn_b,
    float* __restrict__ emb,           // [64,2048] (ws)
    float* __restrict__ graph_out)     // [64,128]  (ws, zeroed here)
{
    __shared__ int                s_cnt[NN];    // 8 KB
    __shared__ float              s_dinv[NN];   // 8 KB
    __shared__ unsigned long long s_acc[NN];    // 16 KB
    const int g = blockIdx.x, tid = threadIdx.x;
    const int4* __restrict__ e4 = (const int4*)(edges + (size_t)g * 2 * NE);

    if (tid < NOISE) graph_out[g * NOISE + tid] = 0.0f;

    int4 ds[16];
    #pragma unroll
    for (int k = 0; k < 16; ++k) ds[k] = e4[4096 + k * 256 + tid];

    for (int n = tid; n < NN; n += 256) { s_cnt[n] = 1; s_acc[n] = 0ull; }
    __syncthreads();

    #pragma unroll
    for (int k = 0; k < 16; ++k) {
        atomicAdd(&s_cnt[ds[k].x], 1);
        atomicAdd(&s_cnt[ds[k].y], 1);
        atomicAdd(&s_cnt[ds[k].z], 1);
        atomicAdd(&s_cnt[ds[k].w], 1);
    }
    __syncthreads();
    for (int n = tid; n < NN; n += 256) s_dinv[n] = rsqrtf((float)s_cnt[n]);
    __syncthreads();

    const float SCALE = 1099511627776.0f;  // 2^40
    #pragma unroll
    for (int k = 0; k < 16; ++k) {
        int4 sr = e4[k * 256 + tid];
        float nx = s_dinv[sr.x] * s_dinv[ds[k].x];
        float ny = s_dinv[sr.y] * s_dinv[ds[k].y];
        float nz = s_dinv[sr.z] * s_dinv[ds[k].z];
        float nw = s_dinv[sr.w] * s_dinv[ds[k].w];
        atomicAdd(&s_acc[ds[k].x], (unsigned long long)(nx * SCALE));
        atomicAdd(&s_acc[ds[k].y], (unsigned long long)(ny * SCALE));
        atomicAdd(&s_acc[ds[k].z], (unsigned long long)(nz * SCALE));
        atomicAdd(&s_acc[ds[k].w], (unsigned long long)(nw * SCALE));
    }
    __syncthreads();

    const float w = gcn_w[0], b = gcn_b[0];
    for (int n = tid; n < NN; n += 256) {
        float di = s_dinv[n];
        float agg = (float)((double)s_acc[n] * 0x1p-40) + di * di;
        emb[(size_t)g * NN + n] = agg * w + b;
    }
}

// ---------------------------------------------------------------------------
// Kernel B: fold emb @ emb_W[0:2048] -> graph_out[64][128].
// 1024 blocks = 64 graphs x 16 node-chunks of 128; LDS-reduce then atomic.
// ---------------------------------------------------------------------------
__global__ __launch_bounds__(256) void fold_kernel(
    const float* __restrict__ emb,       // [64,2048]
    const float* __restrict__ emb_W,     // [2089,128]
    float* __restrict__ graph_out)       // [64,128], zeroed by agg_kernel
{
    __shared__ float s_e[128];
    __shared__ float s_red[128];
    const int tid = threadIdx.x;
    const int g = blockIdx.x >> 4, chunk = blockIdx.x & 15;
    const int n0 = chunk * 128;
    if (tid < 128) s_e[tid] = emb[(size_t)g * NN + n0 + tid];
    __syncthreads();
    const int c = tid & 127, h = tid >> 7;
    const float* __restrict__ Wp = emb_W + (size_t)(n0 + h * 64) * NOISE + c;
    const float* __restrict__ ep = s_e + h * 64;
    float a0 = 0.f, a1 = 0.f, a2 = 0.f, a3 = 0.f;
    #pragma unroll
    for (int i = 0; i < 64; i += 4) {
        a0 = fmaf(ep[i + 0], Wp[(i + 0) * NOISE], a0);
        a1 = fmaf(ep[i + 1], Wp[(i + 1) * NOISE], a1);
        a2 = fmaf(ep[i + 2], Wp[(i + 2) * NOISE], a2);
        a3 = fmaf(ep[i + 3], Wp[(i + 3) * NOISE], a3);
    }
    float acc = (a0 + a1) + (a2 + a3);
    if (h == 1) s_red[c] = acc;
    __syncthreads();
    if (h == 0) atomicAdd(&graph_out[g * NOISE + c], acc + s_red[c]);
}

// ---------------------------------------------------------------------------
// Kernel C: main batched kernel (R6 best-known config). 32 rows/block.
// Phase 1: (2 cols {j,j+16} x 2 rows)/thread, bank-spread LDS strides.
// Phase 2: 2 cols/thread, row metadata from LDS broadcasts, graph_out
// gathers hoisted/batched for MLP.
// ---------------------------------------------------------------------------
#define ROWS 32
__global__ __launch_bounds__(256, 3) void main_kernel(
    const int* __restrict__ bg,          // [B]
    const float* __restrict__ chain,     // [B]
    const float* __restrict__ trig_in,   // [B,64]
    const float* __restrict__ txs,       // [B,8]
    const float* __restrict__ trig_W,    // [64,32]
    const float* __restrict__ trig_b,    // [32]
    const float* __restrict__ emb_W,     // [2089,128]
    const float* __restrict__ emb_b,     // [128]
    const float* __restrict__ graph_out, // [64,128]
    float* __restrict__ out)             // [B,128]
{
    __shared__ float s_td[ROWS * 68];    // trigger rows, stride 68 (8.7 KB)
    __shared__ float s_twT[32 * 68];     // trig_W^T [j][i], stride 68 (8.7 KB)
    __shared__ float s_trig[ROWS * 36];  // relu'd trig, stride 36 (4.6 KB)
    __shared__ float s_tx[ROWS * TXD];   // 1 KB
    __shared__ float s_ch[ROWS];
    __shared__ int   s_gi[ROWS];

    const int tid = threadIdx.x;
    const int row0 = blockIdx.x * ROWS;

    // --- stage trigger rows: 32x64 floats = 512 float4 ---
    {
        const float4* __restrict__ gsrc =
            (const float4*)(trig_in + (size_t)row0 * META);
        #pragma unroll
        for (int k = 0; k < 2; ++k) {
            int t = tid + k * 256;
            int r = t >> 4, i4 = t & 15;
            *(float4*)&s_td[r * 68 + i4 * 4] = gsrc[t];
        }
    }
    // --- stage trig_W transposed: 512 float4, scatter ---
    {
        const float4* __restrict__ gsrc = (const float4*)trig_W;
        #pragma unroll
        for (int k = 0; k < 2; ++k) {
            int t = tid + k * 256;
            int i = t >> 3, j4 = (t & 7) * 4;
            float4 v = gsrc[t];
            s_twT[(j4 + 0) * 68 + i] = v.x;
            s_twT[(j4 + 1) * 68 + i] = v.y;
            s_twT[(j4 + 2) * 68 + i] = v.z;
            s_twT[(j4 + 3) * 68 + i] = v.w;
        }
    }
    // --- stage row metadata: tx (64 float4), chain, graph idx ---
    if (tid < 64) {
        int r = tid >> 1, k4 = (tid & 1) * 4;
        *(float4*)&s_tx[r * TXD + k4] =
            ((const float4*)(txs + (size_t)row0 * TXD))[tid];
    } else if (tid < 96) {
        int r = tid - 64;
        s_ch[r] = chain[row0 + r];
    } else if (tid < 128) {
        int r = tid - 96;
        s_gi[r] = bg[row0 + r];
    }

    // --- per-thread column-pair weights (overlap with staging latency) ---
    const int n0 = (tid & 63) * 2;
    float2 w2[32], w3[TXD];
    #pragma unroll
    for (int j = 0; j < 32; ++j)
        w2[j] = *(const float2*)&emb_W[(size_t)(2049 + j) * NOISE + n0];
    #pragma unroll
    for (int k = 0; k < TXD; ++k)
        w3[k] = *(const float2*)&emb_W[(size_t)(2081 + k) * NOISE + n0];
    const float2 w1   = *(const float2*)&emb_W[(size_t)2048 * NOISE + n0];
    const float2 bias = *(const float2*)&emb_b[n0];

    __syncthreads();

    // --- phase 1: trig = relu(td @ trig_W + b); cols {j0, j0+16} x 2 rows ---
    {
        const int j0 = tid & 15;
        const int r0 = (tid >> 4) * 2;
        const float* __restrict__ tw0 = s_twT + j0 * 68;
        const float* __restrict__ tw1 = s_twT + (j0 + 16) * 68;
        const float* __restrict__ td0 = s_td + r0 * 68;
        const float* __restrict__ td1 = s_td + (r0 + 1) * 68;
        float b0 = trig_b[j0], b1 = trig_b[j0 + 16];
        float a00 = b0, a01 = b1, a10 = b0, a11 = b1;
        #pragma unroll
        for (int i = 0; i < META; i += 4) {
            float4 u0 = *(const float4*)(tw0 + i);
            float4 u1 = *(const float4*)(tw1 + i);
            float4 t0 = *(const float4*)(td0 + i);
            float4 t1 = *(const float4*)(td1 + i);
            a00 = fmaf(t0.x, u0.x, a00); a00 = fmaf(t0.y, u0.y, a00);
            a00 = fmaf(t0.z, u0.z, a00); a00 = fmaf(t0.w, u0.w, a00);
            a01 = fmaf(t0.x, u1.x, a01); a01 = fmaf(t0.y, u1.y, a01);
            a01 = fmaf(t0.z, u1.z, a01); a01 = fmaf(t0.w, u1.w, a01);
            a10 = fmaf(t1.x, u0.x, a10); a10 = fmaf(t1.y, u0.y, a10);
            a10 = fmaf(t1.z, u0.z, a10); a10 = fmaf(t1.w, u0.w, a10);
            a11 = fmaf(t1.x, u1.x, a11); a11 = fmaf(t1.y, u1.y, a11);
            a11 = fmaf(t1.z, u1.z, a11); a11 = fmaf(t1.w, u1.w, a11);
        }
        s_trig[r0 * 36 + j0]            = fmaxf(a00, 0.f);
        s_trig[r0 * 36 + j0 + 16]       = fmaxf(a01, 0.f);
        s_trig[(r0 + 1) * 36 + j0]      = fmaxf(a10, 0.f);
        s_trig[(r0 + 1) * 36 + j0 + 16] = fmaxf(a11, 0.f);
    }
    __syncthreads();

    // --- phase 2: 8 rows x 2 cols per thread ---
    const int wv = tid >> 6;   // rows wave-uniform -> LDS broadcasts
    int   gs[8];
    float chs[8];
    #pragma unroll
    for (int p = 0; p < 8; ++p) {
        const int r = p * 4 + wv;
        gs[p]  = s_gi[r];
        chs[p] = s_ch[r];
    }
    float2 go[8];
    #pragma unroll
    for (int p = 0; p < 8; ++p)
        go[p] = *(const float2*)&graph_out[gs[p] * NOISE + n0];

    #pragma unroll
    for (int p = 0; p < 8; ++p) {
        const int r = p * 4 + wv;
        const int row = row0 + r;
        float ax = bias.x + go[p].x + chs[p] * w1.x;
        float ay = bias.y + go[p].y + chs[p] * w1.y;
        const float4* __restrict__ tx4 = (const float4*)(s_tx + r * TXD);
        float4 t0 = tx4[0], t1 = tx4[1];
        ax = fmaf(t0.x, w3[0].x, ax); ay = fmaf(t0.x, w3[0].y, ay);
        ax = fmaf(t0.y, w3[1].x, ax); ay = fmaf(t0.y, w3[1].y, ay);
        ax = fmaf(t0.z, w3[2].x, ax); ay = fmaf(t0.z, w3[2].y, ay);
        ax = fmaf(t0.w, w3[3].x, ax); ay = fmaf(t0.w, w3[3].y, ay);
        ax = fmaf(t1.x, w3[4].x, ax); ay = fmaf(t1.x, w3[4].y, ay);
        ax = fmaf(t1.y, w3[5].x, ax); ay = fmaf(t1.y, w3[5].y, ay);
        ax = fmaf(t1.z, w3[6].x, ax); ay = fmaf(t1.z, w3[6].y, ay);
        ax = fmaf(t1.w, w3[7].x, ax); ay = fmaf(t1.w, w3[7].y, ay);
        const float* __restrict__ tg = s_trig + r * 36;
        #pragma unroll
        for (int q = 0; q < 8; ++q) {
            float4 t4 = *(const float4*)(tg + q * 4);   // broadcast b128
            ax = fmaf(t4.x, w2[4 * q + 0].x, ax); ay = fmaf(t4.x, w2[4 * q + 0].y, ay);
            ax = fmaf(t4.y, w2[4 * q + 1].x, ax); ay = fmaf(t4.y, w2[4 * q + 1].y, ay);
            ax = fmaf(t4.z, w2[4 * q + 2].x, ax); ay = fmaf(t4.z, w2[4 * q + 2].y, ay);
            ax = fmaf(t4.w, w2[4 * q + 3].x, ax); ay = fmaf(t4.w, w2[4 * q + 3].y, ay);
        }
        *(float2*)&out[(size_t)row * NOISE + n0] = make_float2(ax, ay);
    }
}

extern "C" void kernel_launch(void* const* d_in, const int* in_sizes, int n_in,
                              void* d_out, int out_size, void* d_ws, size_t ws_size,
                              hipStream_t stream) {
    const int*   bg      = (const int*)d_in[0];
    const float* chain   = (const float*)d_in[1];
    const float* trig_in = (const float*)d_in[2];
    const float* txs     = (const float*)d_in[3];
    const int*   edges   = (const int*)d_in[4];
    const float* gcn_w   = (const float*)d_in[5];
    const float* gcn_b   = (const float*)d_in[6];
    const float* trig_W  = (const float*)d_in[7];
    const float* trig_b  = (const float*)d_in[8];
    const float* emb_W   = (const float*)d_in[9];
    const float* emb_b   = (const float*)d_in[10];
    float* out = (float*)d_out;

    float* graph_out = (float*)d_ws;                 // 64*128 floats = 32 KB
    float* emb       = (float*)d_ws + NG * NOISE;    // 64*2048 floats = 512 KB

    agg_kernel<<<NG, 256, 0, stream>>>(edges, gcn_w, gcn_b, emb, graph_out);
    fold_kernel<<<NG * 16, 256, 0, stream>>>(emb, emb_W, graph_out);
    main_kernel<<<BB / ROWS, 256, 0, stream>>>(bg, chain, trig_in, txs, trig_W,
                                               trig_b, emb_W, emb_b, graph_out, out);
}